// Round 9
// baseline (175.136 us; speedup 1.0000x reference)
//
#include <hip/hip_runtime.h>
#include <math.h>

typedef unsigned short u16;
typedef short bf16x8 __attribute__((ext_vector_type(8)));   // 8 bf16 in 4 VGPR
typedef float f32x4 __attribute__((ext_vector_type(4)));
typedef u16 u16x4 __attribute__((ext_vector_type(4)));

#define RATIO 0.0625f   // 256^-0.5
#define EPSK 1e-4f
#define LOG2E 1.44269504f

__device__ __forceinline__ float bf2f(u16 u) {
  return __uint_as_float(((unsigned)u) << 16);
}
__device__ __forceinline__ u16 f2bf(float f) {
  unsigned x = __float_as_uint(f);
  x = x + 0x7fffu + ((x >> 16) & 1u);   // RNE
  return (u16)(x >> 16);
}
__device__ __forceinline__ unsigned cvtpk(float a, float b) {  // [lo=bf16(a), hi=bf16(b)]
  unsigned d;
  asm("v_cvt_pk_bf16_f32 %0, %1, %2" : "=v"(d) : "v"(a), "v"(b));
  return d;
}

using as1v = __attribute__((address_space(1))) void;
using as3v = __attribute__((address_space(3))) void;
__device__ __forceinline__ void gl_lds16(const void* g, void* l) {
  __builtin_amdgcn_global_load_lds((as1v*)g, (as3v*)l, 16, 0, 0);
}

// ---------------- all f32 -> bf16 conversions in one launch ----------------
__global__ __launch_bounds__(256) void cvt_all(
    const float* __restrict__ X, const float* __restrict__ Wq, const float* __restrict__ Wk,
    const float* __restrict__ Wv, const float* __restrict__ Wff, const float* __restrict__ proj,
    u16* __restrict__ Xbf, u16* __restrict__ Wqkv, u16* __restrict__ Wffb, u16* __restrict__ Pbf) {
  long bid = blockIdx.x;
  const float* src;
  u16* dst;
  long off;
  float sc = 1.f;
  if (bid < 8192) { src = X; dst = Xbf; off = bid; }
  else if (bid < 9216) { src = Wq; dst = Wqkv; off = bid - 8192; }
  else if (bid < 10240) { src = Wk; dst = Wqkv + 1048576; off = bid - 9216; }
  else if (bid < 11264) { src = Wv; dst = Wqkv + 2097152; off = bid - 10240; }
  else if (bid < 12288) { src = Wff; dst = Wffb; off = bid - 11264; }
  else { src = proj; dst = Pbf; off = bid - 12288; sc = 0.125f; }
  long i = (off * 256 + threadIdx.x) * 4;
  f32x4 v = *(const f32x4*)(src + i);
  u16x4 o;
#pragma unroll
  for (int j = 0; j < 4; ++j) o[j] = f2bf(v[j] * sc);
  *(u16x4*)(dst + i) = o;
}

// =====================================================================
// gemm256p (qkv): 256x256 tile, BK=64, 8 waves (2M x 4N), per-wave
// 128x64 (m201 geometry). 2 LDS buffers x [A|B] x 2 K-halves (128 KB).
// One PHASE per K-half: {12 ds_read, stage 2 half-units (3 phases
// ahead), lgkm(8), barrier, lgkm(0)+schedbar, setprio(1), 32 MFMA,
// setprio(0), barrier}. Counted vmcnt(8) every phase (tail: 4, 0).
// Staging schedule: phase t.k0 stages (t+1).k1, t.k1 stages (t+2).k0
// -> the slot written always closed its readers >=1 barrier ago.
// Swizzle (64B rows): read col-group hi ^ ((lo>>1)&3), source
// pre-swizzled; conflict-free by construction.
// =====================================================================
template <int NB>
__global__ __launch_bounds__(512, 2) void gemm256p(
    const u16* __restrict__ A, const u16* __restrict__ Bw,
    const float* __restrict__ bq, const float* __restrict__ bk,
    const float* __restrict__ bv, const float* __restrict__ mask,
    u16* __restrict__ Q, u16* __restrict__ Kb, u16* __restrict__ Vt) {
  // elems layout per buffer (32768): [A k0:0-8191][A k1:8192-][B k0:16384-][B k1:24576-]
  __shared__ __align__(16) u16 lds[2 * 32768];  // 128 KB
  const int nt = 16;  // K = 1024, BK = 64
  int tid = threadIdx.x;
  int l = tid & 63, w = tid >> 6;
  int wm = w >> 2, wn = w & 3;
  int lo = l & 15, hi = l >> 4;
  int bid = blockIdx.x;
  int swz = (bid & 7) * ((NB * 32) / 8) + (bid >> 3);  // bijective XCD swizzle (grid%8==0)
  long m0 = (long)(swz / NB) * 256;
  long c0 = (long)(swz % NB) * 256;
  f32x4 acc[8][4] = {};

  // stage one half-unit: (tile t, khalf kh, ab: 0=A 1=B). 2 loads/thread;
  // each issue writes a contiguous 1KB LDS block (16 rows x 64B), source
  // col pre-swizzled so that read-side XOR lands on linear data.
  auto stageU = [&](int t, int kh, int ab) {
    const u16* src = ab ? Bw : A;
    long b0 = ab ? c0 : m0;
    u16* dst = (u16*)lds + (t & 1) * 32768 + ab * 16384 + kh * 8192;
    long k0 = (long)t * 64 + kh * 32;
#pragma unroll
    for (int j = 0; j < 2; ++j) {
      int blk = w + j * 8;            // 16 blocks of 16 rows
      int row = blk * 16 + (l >> 2);
      int s = l & 3;                  // 16B slot within 64B row
      int g = (s ^ ((row >> 1) & 3)) * 8;  // pre-swizzled source elem group
      gl_lds16(src + (b0 + row) * 1024 + k0 + g, dst + blk * 512 + l * 8);
    }
  };

  // prologue: units in consumption order (0,k0),(0,k1),(1,k0) = 12 loads
  stageU(0, 0, 0); stageU(0, 0, 1);
  stageU(0, 1, 0); stageU(0, 1, 1);
  stageU(1, 0, 0); stageU(1, 0, 1);
  asm volatile("s_waitcnt vmcnt(8)" ::: "memory");  // (0,k0) complete
  __builtin_amdgcn_s_barrier();
  __builtin_amdgcn_sched_barrier(0);

  int cg = (lo >> 1) & 3;
  for (int t = 0; t < nt; ++t) {
#pragma unroll
    for (int kh = 0; kh < 2; ++kh) {
      const u16* Au = (const u16*)lds + (t & 1) * 32768 + kh * 8192;
      const u16* Bu = (const u16*)lds + (t & 1) * 32768 + 16384 + kh * 8192;
      bf16x8 areg[8], breg[4];
#pragma unroll
      for (int m = 0; m < 8; ++m) {
        int row = wm * 128 + m * 16 + lo;
        areg[m] = *(const bf16x8*)(Au + row * 32 + ((hi ^ cg) * 8));
      }
#pragma unroll
      for (int n = 0; n < 4; ++n) {
        int row = wn * 64 + n * 16 + lo;
        breg[n] = *(const bf16x8*)(Bu + row * 32 + ((hi ^ cg) * 8));
      }
      // stage 3 phases ahead
      if (kh == 0) {
        if (t + 1 < nt) { stageU(t + 1, 1, 0); stageU(t + 1, 1, 1); }
      } else {
        if (t + 2 < nt) { stageU(t + 2, 0, 0); stageU(t + 2, 0, 1); }
      }
      // counted vmcnt: force the unit needed NEXT phase complete
      if (t < 14 || (t == 14 && kh == 0)) {
        asm volatile("s_waitcnt vmcnt(8)" ::: "memory");
      } else if (t == 14) {
        asm volatile("s_waitcnt vmcnt(4)" ::: "memory");
      } else if (kh == 0) {
        asm volatile("s_waitcnt vmcnt(0)" ::: "memory");
      }
      asm volatile("s_waitcnt lgkmcnt(8)" ::: "memory");
      __builtin_amdgcn_s_barrier();
      asm volatile("s_waitcnt lgkmcnt(0)" ::: "memory");
      __builtin_amdgcn_sched_barrier(0);
      __builtin_amdgcn_s_setprio(1);
#pragma unroll
      for (int m = 0; m < 8; ++m)
#pragma unroll
        for (int n = 0; n < 4; ++n)
          acc[m][n] = __builtin_amdgcn_mfma_f32_16x16x32_bf16(areg[m], breg[n],
                                                              acc[m][n], 0, 0, 0);
      __builtin_amdgcn_s_setprio(0);
      __builtin_amdgcn_s_barrier();
      __builtin_amdgcn_sched_barrier(0);
    }
  }

  // ---- epilogue (qkv) ----
  long rowb = m0 + wm * 128;
  int wsel = (int)(c0 >> 10);  // 0=Q 1=K 2=V (256-col tile never straddles)
  long cw = (c0 & 1023) + wn * 64;
  if (wsel < 2) {
    const float* bias = wsel ? bk : bq;
    u16* O = wsel ? Kb : Q;
#pragma unroll
    for (int mf = 0; mf < 8; ++mf)
#pragma unroll
      for (int nf = 0; nf < 4; ++nf) {
        long col = cw + nf * 16 + lo;
        float bi = bias[col];
#pragma unroll
        for (int r = 0; r < 4; ++r) {
          long row = rowb + mf * 16 + hi * 4 + r;
          O[row * 1024 + col] = f2bf(acc[mf][nf][r] + bi);
        }
      }
  } else {
#pragma unroll
    for (int mf = 0; mf < 8; ++mf) {
      long t4 = rowb + mf * 16 + hi * 4;  // 4 consecutive tokens
      long b = t4 >> 12;
      long nn = t4 & 4095;
#pragma unroll
      for (int nf = 0; nf < 4; ++nf) {
        long col = cw + nf * 16 + lo;
        float bi = bv[col];
        long h = col >> 6, e = col & 63;
        u16x4 pk;
#pragma unroll
        for (int r = 0; r < 4; ++r) pk[r] = f2bf((acc[mf][nf][r] + bi) * mask[t4 + r]);
        *(u16x4*)&Vt[((b * 16 + h) * 64 + e) * 4096 + nn] = pk;
      }
    }
  }
}

// =====================================================================
// Ring GEMM (R5-proven) — used for ff: 256x128 tile, BK=64, 8 waves,
// ring-of-3 LDS, ONE barrier + ONE counted vmcnt(6) per K-tile.
// =====================================================================
template <int EPI, int NB>
__global__ __launch_bounds__(512, 1) void gemmring(
    const u16* __restrict__ A, const u16* __restrict__ Bw,
    const float* __restrict__ bq, const float* __restrict__ bk,
    const float* __restrict__ bv, const float* __restrict__ mask,
    u16* __restrict__ Q, u16* __restrict__ Kb, u16* __restrict__ Vt,
    float* __restrict__ Of, const float* __restrict__ bff) {
  __shared__ __align__(16) u16 lds[3 * 24576];  // 144 KB
  const int nt = 16;
  int tid = threadIdx.x;
  int l = tid & 63, w = tid >> 6;
  int wm = w >> 1, wn = w & 1;
  int lo = l & 15, hi = l >> 4;
  int bid = blockIdx.x;
  int swz = (bid & 7) * ((NB * 32) / 8) + (bid >> 3);
  long m0 = (long)(swz / NB) * 256;
  long c0 = (long)(swz % NB) * 128;
  int srow = tid >> 3;
  int sce = ((tid & 7) ^ ((tid >> 3) & 7)) * 8;
  f32x4 acc[4][4] = {};

  auto stageA = [&](int t) {
    u16* ub = (u16*)lds + (t % 3) * 24576;
    long k0 = (long)t * 64;
#pragma unroll
    for (int u = 0; u < 2; ++u)
#pragma unroll
      for (int j = 0; j < 2; ++j) {
        long row = m0 + u * 128 + j * 64 + srow;
        gl_lds16(A + row * 1024 + k0 + sce, ub + u * 8192 + j * 4096 + tid * 8);
      }
  };
  auto stageB = [&](int t) {
    u16* ub = (u16*)lds + (t % 3) * 24576 + 16384;
    long k0 = (long)t * 64;
#pragma unroll
    for (int j = 0; j < 2; ++j) {
      long row = c0 + j * 64 + srow;
      gl_lds16(Bw + row * 1024 + k0 + sce, ub + j * 4096 + tid * 8);
    }
  };

  stageA(0); stageB(0);
  stageA(1); stageB(1);

  int arb = (wm & 1) * 64;
  for (int t = 0; t < nt; ++t) {
    if (t < nt - 1) {
      asm volatile("s_waitcnt vmcnt(6)" ::: "memory");
    } else {
      asm volatile("s_waitcnt vmcnt(0)" ::: "memory");
    }
    __builtin_amdgcn_s_barrier();
    __builtin_amdgcn_sched_barrier(0);
    const u16* Au = (const u16*)lds + (t % 3) * 24576 + (wm >> 1) * 8192;
    const u16* Bu = (const u16*)lds + (t % 3) * 24576 + 16384;
    bf16x8 areg[4][2], breg[4][2];
#pragma unroll
    for (int mf = 0; mf < 4; ++mf) {
      int lrow = arb + mf * 16 + lo;
#pragma unroll
      for (int kk = 0; kk < 2; ++kk)
        areg[mf][kk] = *(const bf16x8*)(Au + lrow * 64 + ((kk * 32 + hi * 8) ^ ((lo & 7) << 3)));
    }
#pragma unroll
    for (int nf = 0; nf < 4; ++nf) {
      int lrow = wn * 64 + nf * 16 + lo;
#pragma unroll
      for (int kk = 0; kk < 2; ++kk)
        breg[nf][kk] = *(const bf16x8*)(Bu + lrow * 64 + ((kk * 32 + hi * 8) ^ ((lo & 7) << 3)));
    }
    if (t + 2 < nt) { stageA(t + 2); stageB(t + 2); }
#pragma unroll
    for (int mf = 0; mf < 4; ++mf)
#pragma unroll
      for (int nf = 0; nf < 4; ++nf)
#pragma unroll
        for (int kk = 0; kk < 2; ++kk)
          acc[mf][nf] = __builtin_amdgcn_mfma_f32_16x16x32_bf16(areg[mf][kk], breg[nf][kk],
                                                                acc[mf][nf], 0, 0, 0);
  }

  long rowb = m0 + wm * 64;
  if (EPI == 0) {
    int wsel = (int)(c0 >> 10);
    long cw = c0 & 1023;
    if (wsel < 2) {
      const float* bias = wsel ? bk : bq;
      u16* O = wsel ? Kb : Q;
#pragma unroll
      for (int mf = 0; mf < 4; ++mf)
#pragma unroll
        for (int nf = 0; nf < 4; ++nf) {
          long col = cw + wn * 64 + nf * 16 + lo;
          float bi = bias[col];
#pragma unroll
          for (int r = 0; r < 4; ++r) {
            long row = rowb + mf * 16 + hi * 4 + r;
            O[row * 1024 + col] = f2bf(acc[mf][nf][r] + bi);
          }
        }
    } else {
#pragma unroll
      for (int mf = 0; mf < 4; ++mf) {
        long t4 = rowb + mf * 16 + hi * 4;
        long b = t4 >> 12;
        long nn = t4 & 4095;
#pragma unroll
        for (int nf = 0; nf < 4; ++nf) {
          long col = cw + wn * 64 + nf * 16 + lo;
          float bi = bv[col];
          long h = col >> 6, e = col & 63;
          u16x4 pk;
#pragma unroll
          for (int r = 0; r < 4; ++r) pk[r] = f2bf((acc[mf][nf][r] + bi) * mask[t4 + r]);
          *(u16x4*)&Vt[((b * 16 + h) * 64 + e) * 4096 + nn] = pk;
        }
      }
    }
  } else {
#pragma unroll
    for (int mf = 0; mf < 4; ++mf)
#pragma unroll
      for (int nf = 0; nf < 4; ++nf) {
        long col = c0 + wn * 64 + nf * 16 + lo;
        float bi = bff[col];
#pragma unroll
        for (int r = 0; r < 4; ++r) {
          long row = rowb + mf * 16 + hi * 4 + r;
          Of[row * 1024 + col] = acc[mf][nf][r] + bi;
        }
      }
  }
}

// =====================================================================
// kctx (online-max): per (bh, 512-token block): recompute kp-tilde in
// LDS with per-wave running max Mw (rescale by exp(Mw_old-Mw_new));
// accumulate ctx/ksum partials + (wave 0) unscaled vsum via ones-MFMA.
// =====================================================================
__global__ __launch_bounds__(512) void kctx(
    const u16* __restrict__ Kg, const u16* __restrict__ Pbf,
    const u16* __restrict__ Vt, const float* __restrict__ mask,
    u16* __restrict__ part, float* __restrict__ part_ks,
    float* __restrict__ part_m, float* __restrict__ part_vs) {
  __shared__ __align__(16) u16 projL[256 * 64];
  __shared__ __align__(16) u16 KL[256 * 64];
  __shared__ __align__(16) u16 VL[64 * 256];
  __shared__ __align__(16) u16 kpL[256 * 64];
  __shared__ float sdiag[256];
  __shared__ float smask[256];
  int tid = threadIdx.x, l = tid & 63, wq = tid >> 6;
  int lo = l & 15, hi = l >> 4;
  int bh = blockIdx.x, ck2 = blockIdx.y;
  int b = bh >> 4, h = bh & 15;
  int rq = wq * 32;
  int rl = l >> 3;
#pragma unroll
  for (int i = 0; i < 4; ++i) {
    int c = i * 8 + wq;
    int row = c * 8 + rl;
    int sc_ = ((l & 7) * 8) ^ ((row & 7) << 3);
    gl_lds16(Pbf + (long)row * 64 + sc_, projL + c * 512);
  }
  bf16x8 ones;
#pragma unroll
  for (int e = 0; e < 8; ++e) ones[e] = (short)0x3F80;
  float Mw = -3.4e38f;
  f32x4 acc2[2][4] = {};
  f32x4 acc_ks[2] = {};
  f32x4 acc_vs[4] = {};
  for (int s = 0; s < 2; ++s) {
    int ck = ck2 * 2 + s;
    long tg0 = (long)b * 4096 + (long)ck * 256;
    if (s) __syncthreads();
#pragma unroll
    for (int i = 0; i < 4; ++i) {
      int c = i * 8 + wq;
      int row = c * 8 + rl;
      int sc_ = ((l & 7) * 8) ^ ((row & 7) << 3);
      gl_lds16(Kg + (tg0 + row) * 1024 + (long)h * 64 + sc_, KL + c * 512);
    }
#pragma unroll
    for (int i = 0; i < 4; ++i) {
      int c = i * 8 + wq;
      int e = 2 * c + (l >> 5);
      int sc_ = ((l & 31) * 8) ^ ((e & 7) << 3);
      gl_lds16(Vt + ((long)bh * 64 + e) * 4096 + (long)ck * 256 + sc_, VL + c * 512);
    }
    asm volatile("s_waitcnt vmcnt(0)" ::: "memory");
    __syncthreads();
    if (tid < 256) {
      float sm = 0.f;
#pragma unroll
      for (int j = 0; j < 8; ++j) {
        bf16x8 v = *(const bf16x8*)(KL + tid * 64 + ((j * 8) ^ ((tid & 7) << 3)));
#pragma unroll
        for (int e = 0; e < 8; ++e) {
          float f = bf2f((u16)v[e]);
          sm += f * f;
        }
      }
      sdiag[tid] = sm * (1.f / 128.f);
      smask[tid] = mask[tg0 + tid];
    }
    __syncthreads();
    for (int sc = 0; sc < 4; ++sc) {
      f32x4 accT[4][2] = {};
#pragma unroll
      for (int kk = 0; kk < 2; ++kk) {
        bf16x8 aK[4], bP[2];
#pragma unroll
        for (int m = 0; m < 4; ++m)
          aK[m] = *(const bf16x8*)(KL + (sc * 64 + m * 16 + lo) * 64 +
                                   ((kk * 32 + hi * 8) ^ ((lo & 7) << 3)));
#pragma unroll
        for (int nf = 0; nf < 2; ++nf)
          bP[nf] = *(const bf16x8*)(projL + (rq + nf * 16 + lo) * 64 +
                                    ((kk * 32 + hi * 8) ^ ((lo & 7) << 3)));
#pragma unroll
        for (int m = 0; m < 4; ++m)
#pragma unroll
          for (int nf = 0; nf < 2; ++nf)
            accT[m][nf] = __builtin_amdgcn_mfma_f32_16x16x32_bf16(aK[m], bP[nf], accT[m][nf], 0, 0, 0);
      }
      float mloc = -3.4e38f;
#pragma unroll
      for (int m = 0; m < 4; ++m) {
        int tb = m * 16 + hi * 4;
#pragma unroll
        for (int r = 0; r < 4; ++r) {
          float mv = smask[sc * 64 + tb + r];
#pragma unroll
          for (int nf = 0; nf < 2; ++nf) mloc = fmaxf(mloc, mv * accT[m][nf][r]);
        }
      }
#pragma unroll
      for (int sft = 1; sft < 64; sft <<= 1) mloc = fmaxf(mloc, __shfl_xor(mloc, sft, 64));
      float nM = fmaxf(Mw, mloc);
      float rs = __builtin_exp2f((Mw - nM) * LOG2E);
#pragma unroll
      for (int m = 0; m < 2; ++m)
#pragma unroll
        for (int q = 0; q < 4; ++q) {
          acc_ks[m][q] *= rs;
#pragma unroll
          for (int nf = 0; nf < 4; ++nf) acc2[m][nf][q] *= rs;
        }
      Mw = nM;
#pragma unroll
      for (int m = 0; m < 4; ++m) {
        int tb = m * 16 + hi * 4;
        float mv[4], dg[4];
#pragma unroll
        for (int r = 0; r < 4; ++r) {
          int tk = sc * 64 + tb + r;
          mv[r] = smask[tk];
          dg[r] = sdiag[tk];
        }
#pragma unroll
        for (int nf = 0; nf < 2; ++nf) {
          int rr = rq + nf * 16 + lo;
          float v[4];
#pragma unroll
          for (int r = 0; r < 4; ++r) {
            float x = mv[r] * accT[m][nf][r] - mv[r] * mv[r] * dg[r] - Mw;
            v[r] = __builtin_exp2f(x * LOG2E);
          }
          uint2 pk;
          pk.x = cvtpk(v[0], v[1]);
          pk.y = cvtpk(v[2], v[3]);
          *(uint2*)(kpL + rr * 64 + (tb ^ ((lo & 7) << 3))) = pk;
        }
      }
#pragma unroll
      for (int kk = 0; kk < 2; ++kk) {
        bf16x8 aC[2], bV[4];
#pragma unroll
        for (int m = 0; m < 2; ++m)
          aC[m] = *(const bf16x8*)(kpL + (rq + m * 16 + lo) * 64 +
                                   ((kk * 32 + hi * 8) ^ ((lo & 7) << 3)));
#pragma unroll
        for (int nf = 0; nf < 4; ++nf)
          bV[nf] = *(const bf16x8*)(VL + (nf * 16 + lo) * 256 +
                                    ((sc * 64 + kk * 32 + hi * 8) ^ ((lo & 7) << 3)));
#pragma unroll
        for (int m = 0; m < 2; ++m) {
          acc_ks[m] = __builtin_amdgcn_mfma_f32_16x16x32_bf16(aC[m], ones, acc_ks[m], 0, 0, 0);
#pragma unroll
          for (int nf = 0; nf < 4; ++nf)
            acc2[m][nf] = __builtin_amdgcn_mfma_f32_16x16x32_bf16(aC[m], bV[nf], acc2[m][nf], 0, 0, 0);
        }
        if (wq == 0) {
#pragma unroll
          for (int nf = 0; nf < 4; ++nf)
            acc_vs[nf] = __builtin_amdgcn_mfma_f32_16x16x32_bf16(ones, bV[nf], acc_vs[nf], 0, 0, 0);
        }
      }
    }
  }
  long pb = ((long)bh * 8 + ck2) * 64;
#pragma unroll
  for (int m = 0; m < 2; ++m) {
    int r0 = rq + m * 16 + hi * 4;
#pragma unroll
    for (int nf = 0; nf < 4; ++nf) {
      int e = nf * 16 + lo;
      uint2 pk;
      pk.x = cvtpk(acc2[m][nf][0], acc2[m][nf][1]);
      pk.y = cvtpk(acc2[m][nf][2], acc2[m][nf][3]);
      *(uint2*)&part[(pb + e) * 256 + r0] = pk;
    }
    if (lo == 0)
      *(f32x4*)&part_ks[((long)bh * 8 + ck2) * 256 + r0] = acc_ks[m];
  }
  if (l == 0) part_m[((long)bh * 8 + ck2) * 8 + wq] = Mw;
  if (wq == 0 && hi == 0) {
#pragma unroll
    for (int nf = 0; nf < 4; ++nf)
      part_vs[((long)bh * 8 + ck2) * 64 + nf * 16 + lo] = acc_vs[nf][0];
  }
}

// ---------------- reduce partials -> ctxb [bh][80][256] bf16 ----------------
__global__ __launch_bounds__(256) void ctx_reduce2(
    const u16* __restrict__ part, const float* __restrict__ part_ks,
    const float* __restrict__ part_m, const float* __restrict__ part_vs,
    u16* __restrict__ ctxb) {
  int bid = blockIdx.x;
  int bh = bid / 80, j = bid % 80;
  int r = threadIdx.x;
  const float* pm = part_m + (long)bh * 64;
  float M = -3.4e38f;
#pragma unroll
  for (int i = 0; i < 64; ++i) M = fmaxf(M, pm[i]);
  int wv = r >> 5;
  float out = 0.f;
  if (j < 64) {
    float s = 0.f, sv = 0.f;
#pragma unroll
    for (int c = 0; c < 8; ++c) {
      s += __builtin_exp2f((pm[c * 8 + wv] - M) * LOG2E) *
           bf2f(part[(((long)bh * 8 + c) * 64 + j) * 256 + r]);
      sv += part_vs[((long)bh * 8 + c) * 64 + j];
    }
    out = RATIO * (s + EPSK * sv);
  } else if (j == 64) {
    float s = 0.f;
#pragma unroll
    for (int c = 0; c < 8; ++c)
      s += __builtin_exp2f((pm[c * 8 + wv] - M) * LOG2E) *
           part_ks[((long)bh * 8 + c) * 256 + r];
    out = RATIO * (s + EPSK * 4096.f);
  }
  ctxb[((long)bh * 80 + j) * 256 + r] = f2bf(out);
}

// =====================================================================
// qattn: per (bh, 128-token block): recompute qp in LDS (dd transposed,
// cross-wave rowmax), then D2[j][tok] = ctxb[j][r]*qp[tok][r]; j=64 row
// is the denominator (in-lane).
// =====================================================================
__global__ __launch_bounds__(256) void qattn(
    const u16* __restrict__ Qg, const u16* __restrict__ Pbf,
    const u16* __restrict__ ctxbg, u16* __restrict__ attn) {
  __shared__ __align__(16) u16 L[69632];
  __shared__ float sdiagq[128];
  __shared__ float sredq[4 * 128];
  u16* projL = L;
  u16* CL = L + 16384;
  u16* QL = L + 36864;
  u16* qpL = L + 36864;
  int tid = threadIdx.x, l = tid & 63, wq = tid >> 6;
  int lo = l & 15, hi = l >> 4;
  int bh = blockIdx.x;
  int b = bh >> 4, h = bh & 15;
  long tokb = (long)b * 4096 + (long)blockIdx.y * 128;
  int rq = wq * 64, tq = wq * 32;
#pragma unroll
  for (int i = 0; i < 8; ++i) {
    int c = wq * 8 + i;
    int row = c * 8 + (l >> 3);
    int sc_ = ((l & 7) * 8) ^ ((row & 7) << 3);
    gl_lds16(Pbf + (long)row * 64 + sc_, projL + c * 512);
  }
#pragma unroll
  for (int i = 0; i < 4; ++i) {
    int c = wq * 4 + i;
    int row = c * 8 + (l >> 3);
    int sc_ = ((l & 7) * 8) ^ ((row & 7) << 3);
    gl_lds16(Qg + (tokb + row) * 1024 + (long)h * 64 + sc_, QL + c * 512);
  }
#pragma unroll
  for (int i = 0; i < 10; ++i) {
    int c = wq * 10 + i;
    int j = 2 * c + (l >> 5);
    int sc_ = ((l & 31) * 8) ^ ((j & 7) << 3);
    gl_lds16(ctxbg + ((long)bh * 80 + j) * 256 + sc_, CL + c * 512);
  }
  asm volatile("s_waitcnt vmcnt(0)" ::: "memory");
  __syncthreads();
  if (tid < 128) {
    float s = 0.f;
#pragma unroll
    for (int j = 0; j < 8; ++j) {
      bf16x8 v = *(const bf16x8*)(QL + tid * 64 + ((j * 8) ^ ((tid & 7) << 3)));
#pragma unroll
      for (int e = 0; e < 8; ++e) {
        float f = bf2f((u16)v[e]);
        s += f * f;
      }
    }
    sdiagq[tid] = s * (1.f / 128.f);
  }
  f32x4 acc[4][8];
#pragma unroll
  for (int m = 0; m < 4; ++m)
#pragma unroll
    for (int nf = 0; nf < 8; ++nf) acc[m][nf] = f32x4{0.f, 0.f, 0.f, 0.f};
#pragma unroll
  for (int kk = 0; kk < 2; ++kk) {
    bf16x8 aP[4], bQ[8];
#pragma unroll
    for (int m = 0; m < 4; ++m)
      aP[m] = *(const bf16x8*)(projL + (rq + m * 16 + lo) * 64 +
                               ((kk * 32 + hi * 8) ^ ((lo & 7) << 3)));
#pragma unroll
    for (int nf = 0; nf < 8; ++nf)
      bQ[nf] = *(const bf16x8*)(QL + (nf * 16 + lo) * 64 +
                                ((kk * 32 + hi * 8) ^ ((lo & 7) << 3)));
#pragma unroll
    for (int m = 0; m < 4; ++m)
#pragma unroll
      for (int nf = 0; nf < 8; ++nf)
        acc[m][nf] = __builtin_amdgcn_mfma_f32_16x16x32_bf16(aP[m], bQ[nf], acc[m][nf], 0, 0, 0);
  }
#pragma unroll
  for (int nf = 0; nf < 8; ++nf) {
    float vm = acc[0][nf][0];
#pragma unroll
    for (int m = 0; m < 4; ++m)
#pragma unroll
      for (int r = 0; r < 4; ++r) vm = fmaxf(vm, acc[m][nf][r]);
    vm = fmaxf(vm, __shfl_xor(vm, 16, 64));
    vm = fmaxf(vm, __shfl_xor(vm, 32, 64));
    if (hi == 0) sredq[wq * 128 + nf * 16 + lo] = vm;
  }
  __syncthreads();
#pragma unroll
  for (int nf = 0; nf < 8; ++nf) {
    int tk = nf * 16 + lo;
    float rm = fmaxf(fmaxf(sredq[tk], sredq[128 + tk]),
                     fmaxf(sredq[256 + tk], sredq[384 + tk]));
    float dg = sdiagq[tk];
#pragma unroll
    for (int m = 0; m < 4; ++m) {
      int r0 = rq + m * 16 + hi * 4;
      float v[4];
#pragma unroll
      for (int r = 0; r < 4; ++r) {
        float x = acc[m][nf][r] - dg - rm;
        v[r] = RATIO * (__builtin_exp2f(x * LOG2E) + EPSK);
      }
      uint2 pk;
      pk.x = cvtpk(v[0], v[1]);
      pk.y = cvtpk(v[2], v[3]);
      *(uint2*)(qpL + tk * 256 + (r0 ^ ((lo & 7) << 3))) = pk;
    }
  }
  __syncthreads();
  f32x4 acc2[5][2];
#pragma unroll
  for (int m = 0; m < 5; ++m)
#pragma unroll
    for (int n = 0; n < 2; ++n) acc2[m][n] = f32x4{0.f, 0.f, 0.f, 0.f};
#pragma unroll
  for (int ks = 0; ks < 8; ++ks) {
    bf16x8 aC[5], bQp[2];
#pragma unroll
    for (int m = 0; m < 5; ++m)
      aC[m] = *(const bf16x8*)(CL + (m * 16 + lo) * 256 +
                               ((ks * 32 + hi * 8) ^ ((lo & 7) << 3)));
#pragma unroll
    for (int n = 0; n < 2; ++n)
      bQp[n] = *(const bf16x8*)(qpL + (tq + n * 16 + lo) * 256 +
                                ((ks * 32 + hi * 8) ^ ((lo & 7) << 3)));
#pragma unroll
    for (int m = 0; m < 5; ++m)
#pragma unroll
      for (int n = 0; n < 2; ++n)
        acc2[m][n] = __builtin_amdgcn_mfma_f32_16x16x32_bf16(aC[m], bQp[n], acc2[m][n], 0, 0, 0);
  }
#pragma unroll
  for (int n = 0; n < 2; ++n) {
    float dv = __shfl(acc2[4][n][0], lo, 64);
    float di = 1.f / dv;
    long tok = tokb + tq + n * 16 + lo;
#pragma unroll
    for (int m = 0; m < 4; ++m) {
      int j0 = m * 16 + hi * 4;
      uint2 pk;
      pk.x = cvtpk(acc2[m][n][0] * di, acc2[m][n][1] * di);
      pk.y = cvtpk(acc2[m][n][2] * di, acc2[m][n][3] * di);
      *(uint2*)&attn[tok * 1024 + (long)h * 64 + j0] = pk;
    }
  }
}

extern "C" void kernel_launch(void* const* d_in, const int* in_sizes, int n_in,
                              void* d_out, int out_size, void* d_ws, size_t ws_size,
                              hipStream_t stream) {
  const float* X = (const float*)d_in[0];
  const float* mask = (const float*)d_in[1];
  const float* Wq = (const float*)d_in[2];
  const float* bq = (const float*)d_in[3];
  const float* Wk = (const float*)d_in[4];
  const float* bk = (const float*)d_in[5];
  const float* Wv = (const float*)d_in[6];
  const float* bv = (const float*)d_in[7];
  const float* Wff = (const float*)d_in[8];
  const float* bff = (const float*)d_in[9];
  const float* proj = (const float*)d_in[10];
  float* out = (float*)d_out;

  char* p = (char*)d_ws;
  u16* Xbf = (u16*)p;   p += 16777216;   // [8192][1024] bf16; reused as attn
  u16* Wqkv = (u16*)p;  p += 6291456;    // [3072][1024]
  u16* Wffb = (u16*)p;  p += 2097152;    // [1024][1024]
  u16* Pbf = (u16*)p;   p += 32768;      // bf16(proj/8) [256][64]
  u16* Qbf = (u16*)p;   p += 16777216;
  u16* Kbf = (u16*)p;   p += 16777216;
  u16* Vt = (u16*)p;    p += 16777216;   // [bh*64+e][4096] (mask applied)
  u16* ctxb = (u16*)p;  p += 1310720;    // [bh][80][256]
  u16* part = (u16*)p;      p += 8388608;  // [bh*8][64][256] bf16
  float* part_ks = (float*)p; p += 262144; // [bh*8][256] f32
  float* part_m = (float*)p;  p += 8192;   // [bh*8][8] f32
  float* part_vs = (float*)p; p += 65536;  // [bh*8][64] f32
  u16* attn = Xbf;

  cvt_all<<<12304, 256, 0, stream>>>(X, Wq, Wk, Wv, Wff, proj, Xbf, Wqkv, Wffb, Pbf);
  gemm256p<12><<<384, 512, 0, stream>>>(Xbf, Wqkv, bq, bk, bv, mask, Qbf, Kbf, Vt);
  kctx<<<dim3(32, 8), 512, 0, stream>>>(Kbf, Pbf, Vt, mask, part, part_ks, part_m, part_vs);
  ctx_reduce2<<<2560, 256, 0, stream>>>(part, part_ks, part_m, part_vs, ctxb);
  qattn<<<dim3(32, 32), 256, 0, stream>>>(Qbf, Pbf, ctxb, attn);
  gemmring<1, 8><<<256, 512, 0, stream>>>(attn, Wffb, nullptr, nullptr, nullptr, nullptr,
                                          nullptr, nullptr, nullptr, out, bff);
}

// Round 10
// 158.457 us; speedup vs baseline: 1.1053x; 1.1053x over previous
//
#include <hip/hip_runtime.h>
#include <math.h>

typedef unsigned short u16;
typedef short bf16x8 __attribute__((ext_vector_type(8)));   // 8 bf16 in 4 VGPR
typedef float f32x4 __attribute__((ext_vector_type(4)));
typedef u16 u16x4 __attribute__((ext_vector_type(4)));

#define RATIO 0.0625f   // 256^-0.5
#define EPSK 1e-4f
#define LOG2E 1.44269504f

__device__ __forceinline__ float bf2f(u16 u) {
  return __uint_as_float(((unsigned)u) << 16);
}
__device__ __forceinline__ u16 f2bf(float f) {
  unsigned x = __float_as_uint(f);
  x = x + 0x7fffu + ((x >> 16) & 1u);   // RNE
  return (u16)(x >> 16);
}
__device__ __forceinline__ unsigned cvtpk(float a, float b) {  // [lo=bf16(a), hi=bf16(b)]
  unsigned d;
  asm("v_cvt_pk_bf16_f32 %0, %1, %2" : "=v"(d) : "v"(a), "v"(b));
  return d;
}

using as1v = __attribute__((address_space(1))) void;
using as3v = __attribute__((address_space(3))) void;
__device__ __forceinline__ void gl_lds16(const void* g, void* l) {
  __builtin_amdgcn_global_load_lds((as1v*)g, (as3v*)l, 16, 0, 0);
}

// ---------------- all f32 -> bf16 conversions in one launch ----------------
__global__ __launch_bounds__(256) void cvt_all(
    const float* __restrict__ X, const float* __restrict__ Wq, const float* __restrict__ Wk,
    const float* __restrict__ Wv, const float* __restrict__ Wff, const float* __restrict__ proj,
    u16* __restrict__ Xbf, u16* __restrict__ Wqkv, u16* __restrict__ Wffb, u16* __restrict__ Pbf) {
  long bid = blockIdx.x;
  const float* src;
  u16* dst;
  long off;
  float sc = 1.f;
  if (bid < 8192) { src = X; dst = Xbf; off = bid; }
  else if (bid < 9216) { src = Wq; dst = Wqkv; off = bid - 8192; }
  else if (bid < 10240) { src = Wk; dst = Wqkv + 1048576; off = bid - 9216; }
  else if (bid < 11264) { src = Wv; dst = Wqkv + 2097152; off = bid - 10240; }
  else if (bid < 12288) { src = Wff; dst = Wffb; off = bid - 11264; }
  else { src = proj; dst = Pbf; off = bid - 12288; sc = 0.125f; }
  long i = (off * 256 + threadIdx.x) * 4;
  f32x4 v = *(const f32x4*)(src + i);
  u16x4 o;
#pragma unroll
  for (int j = 0; j < 4; ++j) o[j] = f2bf(v[j] * sc);
  *(u16x4*)(dst + i) = o;
}

// =====================================================================
// Ring GEMM (R5-proven): 256x128 tile, BK=64, 8 waves (4M x 2N), 64x64
// per wave. Ring-of-3 LDS slots (144 KB). ONE barrier + ONE counted
// vmcnt(6) per K-tile; staging runs 2 tiles ahead. Read-side XOR swizzle
// with pre-swizzled global source (0 bank conflicts). EPI 0=qkv, 1=ff.
// =====================================================================
template <int EPI, int NB>
__global__ __launch_bounds__(512, 1) void gemmring(
    const u16* __restrict__ A, const u16* __restrict__ Bw,
    const float* __restrict__ bq, const float* __restrict__ bk,
    const float* __restrict__ bv, const float* __restrict__ mask,
    u16* __restrict__ Q, u16* __restrict__ Kb, u16* __restrict__ Vt,
    float* __restrict__ Of, const float* __restrict__ bff) {
  __shared__ __align__(16) u16 lds[3 * 24576];  // 144 KB: slot = [A 256x64 | B 128x64]
  const int nt = 16;  // K = 1024, BK = 64
  int tid = threadIdx.x;
  int l = tid & 63, w = tid >> 6;
  int wm = w >> 1, wn = w & 1;
  int lo = l & 15, hi = l >> 4;
  int bid = blockIdx.x;
  int swz = (bid & 7) * ((NB * 32) / 8) + (bid >> 3);  // bijective XCD swizzle (grid%8==0)
  long m0 = (long)(swz / NB) * 256;
  long c0 = (long)(swz % NB) * 128;
  int srow = tid >> 3;                              // staging row 0..63
  int sce = ((tid & 7) ^ ((tid >> 3) & 7)) * 8;     // pre-swizzled source col
  f32x4 acc[4][4] = {};

  auto stageA = [&](int t) {
    u16* ub = (u16*)lds + (t % 3) * 24576;
    long k0 = (long)t * 64;
#pragma unroll
    for (int u = 0; u < 2; ++u)
#pragma unroll
      for (int j = 0; j < 2; ++j) {
        long row = m0 + u * 128 + j * 64 + srow;
        gl_lds16(A + row * 1024 + k0 + sce, ub + u * 8192 + j * 4096 + tid * 8);
      }
  };
  auto stageB = [&](int t) {
    u16* ub = (u16*)lds + (t % 3) * 24576 + 16384;
    long k0 = (long)t * 64;
#pragma unroll
    for (int j = 0; j < 2; ++j) {
      long row = c0 + j * 64 + srow;
      gl_lds16(Bw + row * 1024 + k0 + sce, ub + j * 4096 + tid * 8);
    }
  };

  // prologue: tiles 0 and 1 in flight (12 loads/thread)
  stageA(0); stageB(0);
  stageA(1); stageB(1);

  int arb = (wm & 1) * 64;
  for (int t = 0; t < nt; ++t) {
    // wait tile t's 6 loads (leave tile t+1's 6 in flight)
    if (t < nt - 1) {
      asm volatile("s_waitcnt vmcnt(6)" ::: "memory");
    } else {
      asm volatile("s_waitcnt vmcnt(0)" ::: "memory");
    }
    __builtin_amdgcn_s_barrier();
    __builtin_amdgcn_sched_barrier(0);
    const u16* Au = (const u16*)lds + (t % 3) * 24576 + (wm >> 1) * 8192;
    const u16* Bu = (const u16*)lds + (t % 3) * 24576 + 16384;
    bf16x8 areg[4][2], breg[4][2];
#pragma unroll
    for (int mf = 0; mf < 4; ++mf) {
      int lrow = arb + mf * 16 + lo;
#pragma unroll
      for (int kk = 0; kk < 2; ++kk)
        areg[mf][kk] = *(const bf16x8*)(Au + lrow * 64 + ((kk * 32 + hi * 8) ^ ((lo & 7) << 3)));
    }
#pragma unroll
    for (int nf = 0; nf < 4; ++nf) {
      int lrow = wn * 64 + nf * 16 + lo;
#pragma unroll
      for (int kk = 0; kk < 2; ++kk)
        breg[nf][kk] = *(const bf16x8*)(Bu + lrow * 64 + ((kk * 32 + hi * 8) ^ ((lo & 7) << 3)));
    }
    // stage tile t+2 into slot (t+2)%3 == (t-1)%3 (its readers finished
    // before barrier(t) above)
    if (t + 2 < nt) { stageA(t + 2); stageB(t + 2); }
    // MFMA; compiler interleaves with partial lgkmcnt waits
#pragma unroll
    for (int mf = 0; mf < 4; ++mf)
#pragma unroll
      for (int nf = 0; nf < 4; ++nf)
#pragma unroll
        for (int kk = 0; kk < 2; ++kk)
          acc[mf][nf] = __builtin_amdgcn_mfma_f32_16x16x32_bf16(areg[mf][kk], breg[nf][kk],
                                                                acc[mf][nf], 0, 0, 0);
  }

  // ---- epilogue ----
  long rowb = m0 + wm * 64;
  if (EPI == 0) {
    int wsel = (int)(c0 >> 10);  // 0=Q 1=K 2=V
    long cw = c0 & 1023;
    if (wsel < 2) {
      const float* bias = wsel ? bk : bq;
      u16* O = wsel ? Kb : Q;
#pragma unroll
      for (int mf = 0; mf < 4; ++mf)
#pragma unroll
        for (int nf = 0; nf < 4; ++nf) {
          long col = cw + wn * 64 + nf * 16 + lo;
          float bi = bias[col];
#pragma unroll
          for (int r = 0; r < 4; ++r) {
            long row = rowb + mf * 16 + hi * 4 + r;
            O[row * 1024 + col] = f2bf(acc[mf][nf][r] + bi);
          }
        }
    } else {
#pragma unroll
      for (int mf = 0; mf < 4; ++mf) {
        long t4 = rowb + mf * 16 + hi * 4;  // 4 consecutive tokens
        long b = t4 >> 12;
        long nn = t4 & 4095;
#pragma unroll
        for (int nf = 0; nf < 4; ++nf) {
          long col = cw + wn * 64 + nf * 16 + lo;
          float bi = bv[col];
          long h = col >> 6, e = col & 63;
          u16x4 pk;
#pragma unroll
          for (int r = 0; r < 4; ++r) pk[r] = f2bf((acc[mf][nf][r] + bi) * mask[t4 + r]);
          *(u16x4*)&Vt[((b * 16 + h) * 64 + e) * 4096 + nn] = pk;
        }
      }
    }
  } else {
#pragma unroll
    for (int mf = 0; mf < 4; ++mf)
#pragma unroll
      for (int nf = 0; nf < 4; ++nf) {
        long col = c0 + wn * 64 + nf * 16 + lo;
        float bi = bff[col];
#pragma unroll
        for (int r = 0; r < 4; ++r) {
          long row = rowb + mf * 16 + hi * 4 + r;
          Of[row * 1024 + col] = acc[mf][nf][r] + bi;
        }
      }
  }
}

// =====================================================================
// kctx (online-max): per (bh, 512-token block = 2 chunks of 256):
// recompute kp-tilde = exp(mask*dd - mask^2*diag - Mw) in LDS with a
// per-wave RUNNING max Mw (rescaling accumulators by exp(Mw_old-Mw_new));
// accumulate ctx/ksum partials + (wave 0) unscaled vsum[e] = sum_n Vm[n,e]
// via a ones-A MFMA. ctx partials stored bf16; ksum/vsum f32.
// =====================================================================
__global__ __launch_bounds__(512) void kctx(
    const u16* __restrict__ Kg, const u16* __restrict__ Pbf,
    const u16* __restrict__ Vt, const float* __restrict__ mask,
    u16* __restrict__ part, float* __restrict__ part_ks,
    float* __restrict__ part_m, float* __restrict__ part_vs) {
  __shared__ __align__(16) u16 projL[256 * 64];  // 32KB
  __shared__ __align__(16) u16 KL[256 * 64];     // 32KB
  __shared__ __align__(16) u16 VL[64 * 256];     // 32KB
  __shared__ __align__(16) u16 kpL[256 * 64];    // 32KB  [r][tok]
  __shared__ float sdiag[256];
  __shared__ float smask[256];
  int tid = threadIdx.x, l = tid & 63, wq = tid >> 6;
  int lo = l & 15, hi = l >> 4;
  int bh = blockIdx.x, ck2 = blockIdx.y;
  int b = bh >> 4, h = bh & 15;
  int rq = wq * 32;  // wave's 32 r-rows
  int rl = l >> 3;
  // stage proj once (4 chunks of 8 rows per wave)
#pragma unroll
  for (int i = 0; i < 4; ++i) {
    int c = i * 8 + wq;
    int row = c * 8 + rl;
    int sc_ = ((l & 7) * 8) ^ ((row & 7) << 3);
    gl_lds16(Pbf + (long)row * 64 + sc_, projL + c * 512);
  }
  bf16x8 ones;
#pragma unroll
  for (int e = 0; e < 8; ++e) ones[e] = (short)0x3F80;
  float Mw = -3.4e38f;
  f32x4 acc2[2][4] = {};
  f32x4 acc_ks[2] = {};
  f32x4 acc_vs[4] = {};
  for (int s = 0; s < 2; ++s) {
    int ck = ck2 * 2 + s;
    long tg0 = (long)b * 4096 + (long)ck * 256;
    if (s) __syncthreads();  // all reads of previous chunk's KL/VL/sdiag done
    // stage K chunk [256][64]
#pragma unroll
    for (int i = 0; i < 4; ++i) {
      int c = i * 8 + wq;
      int row = c * 8 + rl;
      int sc_ = ((l & 7) * 8) ^ ((row & 7) << 3);
      gl_lds16(Kg + (tg0 + row) * 1024 + (long)h * 64 + sc_, KL + c * 512);
    }
    // stage Vt tile [64 e][256 n]
#pragma unroll
    for (int i = 0; i < 4; ++i) {
      int c = i * 8 + wq;
      int e = 2 * c + (l >> 5);
      int sc_ = ((l & 31) * 8) ^ ((e & 7) << 3);
      gl_lds16(Vt + ((long)bh * 64 + e) * 4096 + (long)ck * 256 + sc_, VL + c * 512);
    }
    asm volatile("s_waitcnt vmcnt(0)" ::: "memory");
    __syncthreads();
    // per-token diag + mask (threads 0-255)
    if (tid < 256) {
      float sm = 0.f;
#pragma unroll
      for (int j = 0; j < 8; ++j) {
        bf16x8 v = *(const bf16x8*)(KL + tid * 64 + ((j * 8) ^ ((tid & 7) << 3)));
#pragma unroll
        for (int e = 0; e < 8; ++e) {
          float f = bf2f((u16)v[e]);
          sm += f * f;
        }
      }
      sdiag[tid] = sm * (1.f / 128.f);
      smask[tid] = mask[tg0 + tid];
    }
    __syncthreads();
    for (int sc = 0; sc < 4; ++sc) {
      // dd: D[tok][r], A = K rows (sc*64..), B = proj rows (rq..rq+31)
      f32x4 accT[4][2] = {};
#pragma unroll
      for (int kk = 0; kk < 2; ++kk) {
        bf16x8 aK[4], bP[2];
#pragma unroll
        for (int m = 0; m < 4; ++m)
          aK[m] = *(const bf16x8*)(KL + (sc * 64 + m * 16 + lo) * 64 +
                                   ((kk * 32 + hi * 8) ^ ((lo & 7) << 3)));
#pragma unroll
        for (int nf = 0; nf < 2; ++nf)
          bP[nf] = *(const bf16x8*)(projL + (rq + nf * 16 + lo) * 64 +
                                    ((kk * 32 + hi * 8) ^ ((lo & 7) << 3)));
#pragma unroll
        for (int m = 0; m < 4; ++m)
#pragma unroll
          for (int nf = 0; nf < 2; ++nf)
            accT[m][nf] = __builtin_amdgcn_mfma_f32_16x16x32_bf16(aK[m], bP[nf], accT[m][nf], 0, 0, 0);
      }
      // online max over mask*dd (wave-wide), rescale accumulators
      float mloc = -3.4e38f;
#pragma unroll
      for (int m = 0; m < 4; ++m) {
        int tb = m * 16 + hi * 4;
#pragma unroll
        for (int r = 0; r < 4; ++r) {
          float mv = smask[sc * 64 + tb + r];
#pragma unroll
          for (int nf = 0; nf < 2; ++nf) mloc = fmaxf(mloc, mv * accT[m][nf][r]);
        }
      }
#pragma unroll
      for (int sft = 1; sft < 64; sft <<= 1) mloc = fmaxf(mloc, __shfl_xor(mloc, sft, 64));
      float nM = fmaxf(Mw, mloc);
      float rs = __builtin_exp2f((Mw - nM) * LOG2E);
#pragma unroll
      for (int m = 0; m < 2; ++m)
#pragma unroll
        for (int q = 0; q < 4; ++q) {
          acc_ks[m][q] *= rs;
#pragma unroll
          for (int nf = 0; nf < 4; ++nf) acc2[m][nf][q] *= rs;
        }
      Mw = nM;
      // kp-tilde epilogue -> kpL[r][tok] (own rows rq..rq+31)
#pragma unroll
      for (int m = 0; m < 4; ++m) {
        int tb = m * 16 + hi * 4;
        float mv[4], dg[4];
#pragma unroll
        for (int r = 0; r < 4; ++r) {
          int tk = sc * 64 + tb + r;
          mv[r] = smask[tk];
          dg[r] = sdiag[tk];
        }
#pragma unroll
        for (int nf = 0; nf < 2; ++nf) {
          int rr = rq + nf * 16 + lo;
          float v[4];
#pragma unroll
          for (int r = 0; r < 4; ++r) {
            float x = mv[r] * accT[m][nf][r] - mv[r] * mv[r] * dg[r] - Mw;
            v[r] = __builtin_exp2f(x * LOG2E);
          }
          uint2 pk;
          pk.x = cvtpk(v[0], v[1]);
          pk.y = cvtpk(v[2], v[3]);
          *(uint2*)(kpL + rr * 64 + (tb ^ ((lo & 7) << 3))) = pk;
        }
      }
      // ctx MFMA: D[r][e] += kp~[r][n] * Vt[e][n]; + ksum via ones;
      // wave 0 also accumulates unscaled vsum[e] = sum_n Vm[n][e]
#pragma unroll
      for (int kk = 0; kk < 2; ++kk) {
        bf16x8 aC[2], bV[4];
#pragma unroll
        for (int m = 0; m < 2; ++m)
          aC[m] = *(const bf16x8*)(kpL + (rq + m * 16 + lo) * 64 +
                                   ((kk * 32 + hi * 8) ^ ((lo & 7) << 3)));
#pragma unroll
        for (int nf = 0; nf < 4; ++nf)
          bV[nf] = *(const bf16x8*)(VL + (nf * 16 + lo) * 256 +
                                    ((sc * 64 + kk * 32 + hi * 8) ^ ((lo & 7) << 3)));
#pragma unroll
        for (int m = 0; m < 2; ++m) {
          acc_ks[m] = __builtin_amdgcn_mfma_f32_16x16x32_bf16(aC[m], ones, acc_ks[m], 0, 0, 0);
#pragma unroll
          for (int nf = 0; nf < 4; ++nf)
            acc2[m][nf] = __builtin_amdgcn_mfma_f32_16x16x32_bf16(aC[m], bV[nf], acc2[m][nf], 0, 0, 0);
        }
        if (wq == 0) {
#pragma unroll
          for (int nf = 0; nf < 4; ++nf)
            acc_vs[nf] = __builtin_amdgcn_mfma_f32_16x16x32_bf16(ones, bV[nf], acc_vs[nf], 0, 0, 0);
        }
      }
    }
  }
  // write partials: part (bf16) [(bh*8+ck2)*64 + e][256 r], ksum f32,
  // per-wave max, wave-0 vsum f32
  long pb = ((long)bh * 8 + ck2) * 64;
#pragma unroll
  for (int m = 0; m < 2; ++m) {
    int r0 = rq + m * 16 + hi * 4;
#pragma unroll
    for (int nf = 0; nf < 4; ++nf) {
      int e = nf * 16 + lo;
      uint2 pk;
      pk.x = cvtpk(acc2[m][nf][0], acc2[m][nf][1]);
      pk.y = cvtpk(acc2[m][nf][2], acc2[m][nf][3]);
      *(uint2*)&part[(pb + e) * 256 + r0] = pk;
    }
    if (lo == 0)
      *(f32x4*)&part_ks[((long)bh * 8 + ck2) * 256 + r0] = acc_ks[m];
  }
  if (l == 0) part_m[((long)bh * 8 + ck2) * 8 + wq] = Mw;
  if (wq == 0 && hi == 0) {
#pragma unroll
    for (int nf = 0; nf < 4; ++nf)
      part_vs[((long)bh * 8 + ck2) * 64 + nf * 16 + lo] = acc_vs[nf][0];
  }
}

// ---------------- reduce partials -> ctxb [bh][80][256] bf16 ----------------
// Reconstructs global key-max M = max over (chunk, wave) Mw; combines with
// exp(Mw - M); applies RATIO and +EPSK terms (eps * vsum for ctx, eps * N
// for ksum). No Vt re-read, no LDS.
__global__ __launch_bounds__(256) void ctx_reduce2(
    const u16* __restrict__ part, const float* __restrict__ part_ks,
    const float* __restrict__ part_m, const float* __restrict__ part_vs,
    u16* __restrict__ ctxb) {
  int bid = blockIdx.x;
  int bh = bid / 80, j = bid % 80;
  int r = threadIdx.x;
  const float* pm = part_m + (long)bh * 64;
  float M = -3.4e38f;
#pragma unroll
  for (int i = 0; i < 64; ++i) M = fmaxf(M, pm[i]);
  int wv = r >> 5;
  float out = 0.f;
  if (j < 64) {
    float s = 0.f, sv = 0.f;
#pragma unroll
    for (int c = 0; c < 8; ++c) {
      s += __builtin_exp2f((pm[c * 8 + wv] - M) * LOG2E) *
           bf2f(part[(((long)bh * 8 + c) * 64 + j) * 256 + r]);
      sv += part_vs[((long)bh * 8 + c) * 64 + j];
    }
    out = RATIO * (s + EPSK * sv);
  } else if (j == 64) {
    float s = 0.f;
#pragma unroll
    for (int c = 0; c < 8; ++c)
      s += __builtin_exp2f((pm[c * 8 + wv] - M) * LOG2E) *
           part_ks[((long)bh * 8 + c) * 256 + r];
    out = RATIO * (s + EPSK * 4096.f);
  }
  ctxb[((long)bh * 80 + j) * 256 + r] = f2bf(out);
}

// =====================================================================
// qattn: per (bh, 128-token block): recompute qp in LDS (dd transposed,
// cross-wave rowmax), then D2[j][tok] = ctxb[j][r]*qp[tok][r]; j=64 row
// is the denominator (in-lane).
// =====================================================================
__global__ __launch_bounds__(256) void qattn(
    const u16* __restrict__ Qg, const u16* __restrict__ Pbf,
    const u16* __restrict__ ctxbg, u16* __restrict__ attn) {
  __shared__ __align__(16) u16 L[69632];  // proj 16384 | ctxb 20480 | Q/qp 32768
  __shared__ float sdiagq[128];
  __shared__ float sredq[4 * 128];
  u16* projL = L;
  u16* CL = L + 16384;
  u16* QL = L + 36864;   // overlaid by qp after the rowmax barrier
  u16* qpL = L + 36864;  // [128 tok][256 r]
  int tid = threadIdx.x, l = tid & 63, wq = tid >> 6;
  int lo = l & 15, hi = l >> 4;
  int bh = blockIdx.x;
  int b = bh >> 4, h = bh & 15;
  long tokb = (long)b * 4096 + (long)blockIdx.y * 128;
  int rq = wq * 64, tq = wq * 32;
  // stage proj (swizzled)
#pragma unroll
  for (int i = 0; i < 8; ++i) {
    int c = wq * 8 + i;
    int row = c * 8 + (l >> 3);
    int sc_ = ((l & 7) * 8) ^ ((row & 7) << 3);
    gl_lds16(Pbf + (long)row * 64 + sc_, projL + c * 512);
  }
  // stage Q tile [128][64] (swizzled)
#pragma unroll
  for (int i = 0; i < 4; ++i) {
    int c = wq * 4 + i;
    int row = c * 8 + (l >> 3);
    int sc_ = ((l & 7) * 8) ^ ((row & 7) << 3);
    gl_lds16(Qg + (tokb + row) * 1024 + (long)h * 64 + sc_, QL + c * 512);
  }
  // stage ctxb tile [80][256] (swizzled)
#pragma unroll
  for (int i = 0; i < 10; ++i) {
    int c = wq * 10 + i;
    int j = 2 * c + (l >> 5);
    int sc_ = ((l & 31) * 8) ^ ((j & 7) << 3);
    gl_lds16(ctxbg + ((long)bh * 80 + j) * 256 + sc_, CL + c * 512);
  }
  asm volatile("s_waitcnt vmcnt(0)" ::: "memory");
  __syncthreads();
  // diag per token (threads 0-127)
  if (tid < 128) {
    float s = 0.f;
#pragma unroll
    for (int j = 0; j < 8; ++j) {
      bf16x8 v = *(const bf16x8*)(QL + tid * 64 + ((j * 8) ^ ((tid & 7) << 3)));
#pragma unroll
      for (int e = 0; e < 8; ++e) {
        float f = bf2f((u16)v[e]);
        s += f * f;
      }
    }
    sdiagq[tid] = s * (1.f / 128.f);
  }
  // dd transposed: D[r][tok], A = proj rows r (wave quadrant), B = Q rows tok
  f32x4 acc[4][8];
#pragma unroll
  for (int m = 0; m < 4; ++m)
#pragma unroll
    for (int nf = 0; nf < 8; ++nf) acc[m][nf] = f32x4{0.f, 0.f, 0.f, 0.f};
#pragma unroll
  for (int kk = 0; kk < 2; ++kk) {
    bf16x8 aP[4], bQ[8];
#pragma unroll
    for (int m = 0; m < 4; ++m)
      aP[m] = *(const bf16x8*)(projL + (rq + m * 16 + lo) * 64 +
                               ((kk * 32 + hi * 8) ^ ((lo & 7) << 3)));
#pragma unroll
    for (int nf = 0; nf < 8; ++nf)
      bQ[nf] = *(const bf16x8*)(QL + (nf * 16 + lo) * 64 +
                                ((kk * 32 + hi * 8) ^ ((lo & 7) << 3)));
#pragma unroll
    for (int m = 0; m < 4; ++m)
#pragma unroll
      for (int nf = 0; nf < 8; ++nf)
        acc[m][nf] = __builtin_amdgcn_mfma_f32_16x16x32_bf16(aP[m], bQ[nf], acc[m][nf], 0, 0, 0);
  }
  // wave-local rowmax per token
#pragma unroll
  for (int nf = 0; nf < 8; ++nf) {
    float vm = acc[0][nf][0];
#pragma unroll
    for (int m = 0; m < 4; ++m)
#pragma unroll
      for (int r = 0; r < 4; ++r) vm = fmaxf(vm, acc[m][nf][r]);
    vm = fmaxf(vm, __shfl_xor(vm, 16, 64));
    vm = fmaxf(vm, __shfl_xor(vm, 32, 64));
    if (hi == 0) sredq[wq * 128 + nf * 16 + lo] = vm;
  }
  __syncthreads();  // also separates QL reads from qp writes
  // final rowmax + epilogue -> qpL[tok][r]
#pragma unroll
  for (int nf = 0; nf < 8; ++nf) {
    int tk = nf * 16 + lo;
    float rm = fmaxf(fmaxf(sredq[tk], sredq[128 + tk]),
                     fmaxf(sredq[256 + tk], sredq[384 + tk]));
    float dg = sdiagq[tk];
#pragma unroll
    for (int m = 0; m < 4; ++m) {
      int r0 = rq + m * 16 + hi * 4;
      float v[4];
#pragma unroll
      for (int r = 0; r < 4; ++r) {
        float x = acc[m][nf][r] - dg - rm;
        v[r] = RATIO * (__builtin_exp2f(x * LOG2E) + EPSK);
      }
      uint2 pk;
      pk.x = cvtpk(v[0], v[1]);
      pk.y = cvtpk(v[2], v[3]);
      *(uint2*)(qpL + tk * 256 + (r0 ^ ((lo & 7) << 3))) = pk;
    }
  }
  __syncthreads();
  // D2[j][tok] = sum_r ctxb[j][r] * qp[tok][r]; wave owns 32 tok
  f32x4 acc2[5][2];
#pragma unroll
  for (int m = 0; m < 5; ++m)
#pragma unroll
    for (int n = 0; n < 2; ++n) acc2[m][n] = f32x4{0.f, 0.f, 0.f, 0.f};
#pragma unroll
  for (int ks = 0; ks < 8; ++ks) {
    bf16x8 aC[5], bQp[2];
#pragma unroll
    for (int m = 0; m < 5; ++m)
      aC[m] = *(const bf16x8*)(CL + (m * 16 + lo) * 256 +
                               ((ks * 32 + hi * 8) ^ ((lo & 7) << 3)));
#pragma unroll
    for (int n = 0; n < 2; ++n)
      bQp[n] = *(const bf16x8*)(qpL + (tq + n * 16 + lo) * 256 +
                                ((ks * 32 + hi * 8) ^ ((lo & 7) << 3)));
#pragma unroll
    for (int m = 0; m < 5; ++m)
#pragma unroll
      for (int n = 0; n < 2; ++n)
        acc2[m][n] = __builtin_amdgcn_mfma_f32_16x16x32_bf16(aC[m], bQp[n], acc2[m][n], 0, 0, 0);
  }
  // epilogue: denom at j=64 (m=4, hi=0, reg=0) -> broadcast via shfl(lane = lo)
#pragma unroll
  for (int n = 0; n < 2; ++n) {
    float dv = __shfl(acc2[4][n][0], lo, 64);
    float di = 1.f / dv;
    long tok = tokb + tq + n * 16 + lo;
#pragma unroll
    for (int m = 0; m < 4; ++m) {
      int j0 = m * 16 + hi * 4;
      uint2 pk;
      pk.x = cvtpk(acc2[m][n][0] * di, acc2[m][n][1] * di);
      pk.y = cvtpk(acc2[m][n][2] * di, acc2[m][n][3] * di);
      *(uint2*)&attn[tok * 1024 + (long)h * 64 + j0] = pk;
    }
  }
}

extern "C" void kernel_launch(void* const* d_in, const int* in_sizes, int n_in,
                              void* d_out, int out_size, void* d_ws, size_t ws_size,
                              hipStream_t stream) {
  const float* X = (const float*)d_in[0];
  const float* mask = (const float*)d_in[1];
  const float* Wq = (const float*)d_in[2];
  const float* bq = (const float*)d_in[3];
  const float* Wk = (const float*)d_in[4];
  const float* bk = (const float*)d_in[5];
  const float* Wv = (const float*)d_in[6];
  const float* bv = (const float*)d_in[7];
  const float* Wff = (const float*)d_in[8];
  const float* bff = (const float*)d_in[9];
  const float* proj = (const float*)d_in[10];
  float* out = (float*)d_out;

  char* p = (char*)d_ws;
  u16* Xbf = (u16*)p;   p += 16777216;   // [8192][1024] bf16; reused as attn
  u16* Wqkv = (u16*)p;  p += 6291456;    // [3072][1024]
  u16* Wffb = (u16*)p;  p += 2097152;    // [1024][1024]
  u16* Pbf = (u16*)p;   p += 32768;      // bf16(proj/8) [256][64]
  u16* Qbf = (u16*)p;   p += 16777216;
  u16* Kbf = (u16*)p;   p += 16777216;
  u16* Vt = (u16*)p;    p += 16777216;   // [bh*64+e][4096] (mask applied)
  u16* ctxb = (u16*)p;  p += 1310720;    // [bh][80][256]
  u16* part = (u16*)p;      p += 8388608;  // [bh*8][64][256] bf16
  float* part_ks = (float*)p; p += 262144; // [bh*8][256] f32
  float* part_m = (float*)p;  p += 8192;   // [bh*8][8] f32
  float* part_vs = (float*)p; p += 65536;  // [bh*8][64] f32
  u16* attn = Xbf;

  cvt_all<<<12304, 256, 0, stream>>>(X, Wq, Wk, Wv, Wff, proj, Xbf, Wqkv, Wffb, Pbf);
  gemmring<0, 24><<<768, 512, 0, stream>>>(Xbf, Wqkv, bq, bk, bv, mask, Qbf, Kbf, Vt, nullptr, nullptr);
  kctx<<<dim3(32, 8), 512, 0, stream>>>(Kbf, Pbf, Vt, mask, part, part_ks, part_m, part_vs);
  ctx_reduce2<<<2560, 256, 0, stream>>>(part, part_ks, part_m, part_vs, ctxb);
  qattn<<<dim3(32, 32), 256, 0, stream>>>(Qbf, Pbf, ctxb, attn);
  gemmring<1, 8><<<256, 512, 0, stream>>>(attn, Wffb, nullptr, nullptr, nullptr, nullptr,
                                          nullptr, nullptr, nullptr, out, bff);
}

// Round 11
// 157.498 us; speedup vs baseline: 1.1120x; 1.0061x over previous
//
#include <hip/hip_runtime.h>
#include <math.h>

typedef unsigned short u16;
typedef short bf16x8 __attribute__((ext_vector_type(8)));   // 8 bf16 in 4 VGPR
typedef float f32x4 __attribute__((ext_vector_type(4)));
typedef u16 u16x4 __attribute__((ext_vector_type(4)));

#define RATIO 0.0625f   // 256^-0.5
#define EPSK 1e-4f
#define LOG2E 1.44269504f

__device__ __forceinline__ float bf2f(u16 u) {
  return __uint_as_float(((unsigned)u) << 16);
}
__device__ __forceinline__ u16 f2bf(float f) {
  unsigned x = __float_as_uint(f);
  x = x + 0x7fffu + ((x >> 16) & 1u);   // RNE
  return (u16)(x >> 16);
}
__device__ __forceinline__ unsigned cvtpk(float a, float b) {  // [lo=bf16(a), hi=bf16(b)]
  unsigned d;
  asm("v_cvt_pk_bf16_f32 %0, %1, %2" : "=v"(d) : "v"(a), "v"(b));
  return d;
}

using as1v = __attribute__((address_space(1))) void;
using as3v = __attribute__((address_space(3))) void;
__device__ __forceinline__ void gl_lds16(const void* g, void* l) {
  __builtin_amdgcn_global_load_lds((as1v*)g, (as3v*)l, 16, 0, 0);
}

// ---------------- all f32 -> bf16 conversions in one launch ----------------
__global__ __launch_bounds__(256) void cvt_all(
    const float* __restrict__ X, const float* __restrict__ Wq, const float* __restrict__ Wk,
    const float* __restrict__ Wv, const float* __restrict__ Wff, const float* __restrict__ proj,
    u16* __restrict__ Xbf, u16* __restrict__ Wqkv, u16* __restrict__ Wffb, u16* __restrict__ Pbf) {
  long bid = blockIdx.x;
  const float* src;
  u16* dst;
  long off;
  float sc = 1.f;
  if (bid < 8192) { src = X; dst = Xbf; off = bid; }
  else if (bid < 9216) { src = Wq; dst = Wqkv; off = bid - 8192; }
  else if (bid < 10240) { src = Wk; dst = Wqkv + 1048576; off = bid - 9216; }
  else if (bid < 11264) { src = Wv; dst = Wqkv + 2097152; off = bid - 10240; }
  else if (bid < 12288) { src = Wff; dst = Wffb; off = bid - 11264; }
  else { src = proj; dst = Pbf; off = bid - 12288; sc = 0.125f; }
  long i = (off * 256 + threadIdx.x) * 4;
  f32x4 v = *(const f32x4*)(src + i);
  u16x4 o;
#pragma unroll
  for (int j = 0; j < 4; ++j) o[j] = f2bf(v[j] * sc);
  *(u16x4*)(dst + i) = o;
}

// =====================================================================
// Ring GEMM (R5-proven): 256x128 tile, BK=64, 8 waves (4M x 2N), 64x64
// per wave. Ring-of-3 LDS slots (144 KB). ONE barrier + ONE counted
// vmcnt(6) per K-tile; staging runs 2 tiles ahead. Read-side XOR swizzle
// with pre-swizzled global source (0 bank conflicts). EPI 0=qkv, 1=ff.
// =====================================================================
template <int EPI, int NB>
__global__ __launch_bounds__(512, 1) void gemmring(
    const u16* __restrict__ A, const u16* __restrict__ Bw,
    const float* __restrict__ bq, const float* __restrict__ bk,
    const float* __restrict__ bv, const float* __restrict__ mask,
    u16* __restrict__ Q, u16* __restrict__ Kb, u16* __restrict__ Vt,
    float* __restrict__ Of, const float* __restrict__ bff) {
  __shared__ __align__(16) u16 lds[3 * 24576];  // 144 KB: slot = [A 256x64 | B 128x64]
  const int nt = 16;  // K = 1024, BK = 64
  int tid = threadIdx.x;
  int l = tid & 63, w = tid >> 6;
  int wm = w >> 1, wn = w & 1;
  int lo = l & 15, hi = l >> 4;
  int bid = blockIdx.x;
  int swz = (bid & 7) * ((NB * 32) / 8) + (bid >> 3);  // bijective XCD swizzle (grid%8==0)
  long m0 = (long)(swz / NB) * 256;
  long c0 = (long)(swz % NB) * 128;
  int srow = tid >> 3;                              // staging row 0..63
  int sce = ((tid & 7) ^ ((tid >> 3) & 7)) * 8;     // pre-swizzled source col
  f32x4 acc[4][4] = {};

  auto stageA = [&](int t) {
    u16* ub = (u16*)lds + (t % 3) * 24576;
    long k0 = (long)t * 64;
#pragma unroll
    for (int u = 0; u < 2; ++u)
#pragma unroll
      for (int j = 0; j < 2; ++j) {
        long row = m0 + u * 128 + j * 64 + srow;
        gl_lds16(A + row * 1024 + k0 + sce, ub + u * 8192 + j * 4096 + tid * 8);
      }
  };
  auto stageB = [&](int t) {
    u16* ub = (u16*)lds + (t % 3) * 24576 + 16384;
    long k0 = (long)t * 64;
#pragma unroll
    for (int j = 0; j < 2; ++j) {
      long row = c0 + j * 64 + srow;
      gl_lds16(Bw + row * 1024 + k0 + sce, ub + j * 4096 + tid * 8);
    }
  };

  // prologue: tiles 0 and 1 in flight (12 loads/thread)
  stageA(0); stageB(0);
  stageA(1); stageB(1);

  int arb = (wm & 1) * 64;
  for (int t = 0; t < nt; ++t) {
    // wait tile t's 6 loads (leave tile t+1's 6 in flight)
    if (t < nt - 1) {
      asm volatile("s_waitcnt vmcnt(6)" ::: "memory");
    } else {
      asm volatile("s_waitcnt vmcnt(0)" ::: "memory");
    }
    __builtin_amdgcn_s_barrier();
    __builtin_amdgcn_sched_barrier(0);
    const u16* Au = (const u16*)lds + (t % 3) * 24576 + (wm >> 1) * 8192;
    const u16* Bu = (const u16*)lds + (t % 3) * 24576 + 16384;
    bf16x8 areg[4][2], breg[4][2];
#pragma unroll
    for (int mf = 0; mf < 4; ++mf) {
      int lrow = arb + mf * 16 + lo;
#pragma unroll
      for (int kk = 0; kk < 2; ++kk)
        areg[mf][kk] = *(const bf16x8*)(Au + lrow * 64 + ((kk * 32 + hi * 8) ^ ((lo & 7) << 3)));
    }
#pragma unroll
    for (int nf = 0; nf < 4; ++nf) {
      int lrow = wn * 64 + nf * 16 + lo;
#pragma unroll
      for (int kk = 0; kk < 2; ++kk)
        breg[nf][kk] = *(const bf16x8*)(Bu + lrow * 64 + ((kk * 32 + hi * 8) ^ ((lo & 7) << 3)));
    }
    // stage tile t+2 into slot (t+2)%3 == (t-1)%3 (its readers finished
    // before barrier(t) above)
    if (t + 2 < nt) { stageA(t + 2); stageB(t + 2); }
    // MFMA; compiler interleaves with partial lgkmcnt waits
#pragma unroll
    for (int mf = 0; mf < 4; ++mf)
#pragma unroll
      for (int nf = 0; nf < 4; ++nf)
#pragma unroll
        for (int kk = 0; kk < 2; ++kk)
          acc[mf][nf] = __builtin_amdgcn_mfma_f32_16x16x32_bf16(areg[mf][kk], breg[nf][kk],
                                                                acc[mf][nf], 0, 0, 0);
  }

  // ---- epilogue ----
  long rowb = m0 + wm * 64;
  if (EPI == 0) {
    int wsel = (int)(c0 >> 10);  // 0=Q 1=K 2=V
    long cw = c0 & 1023;
    if (wsel < 2) {
      const float* bias = wsel ? bk : bq;
      u16* O = wsel ? Kb : Q;
#pragma unroll
      for (int mf = 0; mf < 4; ++mf)
#pragma unroll
        for (int nf = 0; nf < 4; ++nf) {
          long col = cw + wn * 64 + nf * 16 + lo;
          float bi = bias[col];
#pragma unroll
          for (int r = 0; r < 4; ++r) {
            long row = rowb + mf * 16 + hi * 4 + r;
            O[row * 1024 + col] = f2bf(acc[mf][nf][r] + bi);
          }
        }
    } else {
#pragma unroll
      for (int mf = 0; mf < 4; ++mf) {
        long t4 = rowb + mf * 16 + hi * 4;  // 4 consecutive tokens
        long b = t4 >> 12;
        long nn = t4 & 4095;
#pragma unroll
        for (int nf = 0; nf < 4; ++nf) {
          long col = cw + wn * 64 + nf * 16 + lo;
          float bi = bv[col];
          long h = col >> 6, e = col & 63;
          u16x4 pk;
#pragma unroll
          for (int r = 0; r < 4; ++r) pk[r] = f2bf((acc[mf][nf][r] + bi) * mask[t4 + r]);
          *(u16x4*)&Vt[((b * 16 + h) * 64 + e) * 4096 + nn] = pk;
        }
      }
    }
  } else {
#pragma unroll
    for (int mf = 0; mf < 4; ++mf)
#pragma unroll
      for (int nf = 0; nf < 4; ++nf) {
        long col = c0 + wn * 64 + nf * 16 + lo;
        float bi = bff[col];
#pragma unroll
        for (int r = 0; r < 4; ++r) {
          long row = rowb + mf * 16 + hi * 4 + r;
          Of[row * 1024 + col] = acc[mf][nf][r] + bi;
        }
      }
  }
}

// =====================================================================
// kctx (online-max): per (bh, 512-token block = 2 chunks of 256):
// recompute kp-tilde in LDS with per-wave running max Mw (rescale by
// exp(Mw_old-Mw_new)); accumulate ctx/ksum partials + (wave 0) unscaled
// vsum via ones-MFMA. proj B-fragments preloaded into REGISTERS
// (layout-identical to the former swizzled-LDS path); no projL buffer.
// =====================================================================
__global__ __launch_bounds__(512) void kctx(
    const u16* __restrict__ Kg, const u16* __restrict__ Pbf,
    const u16* __restrict__ Vt, const float* __restrict__ mask,
    u16* __restrict__ part, float* __restrict__ part_ks,
    float* __restrict__ part_m, float* __restrict__ part_vs) {
  __shared__ __align__(16) u16 KL[256 * 64];     // 32KB
  __shared__ __align__(16) u16 VL[64 * 256];     // 32KB
  __shared__ __align__(16) u16 kpL[256 * 64];    // 32KB  [r][tok]
  __shared__ float sdiag[256];
  __shared__ float smask[256];
  int tid = threadIdx.x, l = tid & 63, wq = tid >> 6;
  int lo = l & 15, hi = l >> 4;
  int bh = blockIdx.x, ck2 = blockIdx.y;
  int b = bh >> 4, h = bh & 15;
  int rq = wq * 32;  // wave's 32 r-rows
  int rl = l >> 3;
  // proj B-fragments (rows rq..rq+31) straight from global into MFMA layout
  bf16x8 bPreg[2][2];
#pragma unroll
  for (int nf = 0; nf < 2; ++nf)
#pragma unroll
    for (int kk = 0; kk < 2; ++kk)
      bPreg[nf][kk] = *(const bf16x8*)(Pbf + (long)(rq + nf * 16 + lo) * 64 + kk * 32 + hi * 8);
  bf16x8 ones;
#pragma unroll
  for (int e = 0; e < 8; ++e) ones[e] = (short)0x3F80;
  float Mw = -3.4e38f;
  f32x4 acc2[2][4] = {};
  f32x4 acc_ks[2] = {};
  f32x4 acc_vs[4] = {};
  for (int s = 0; s < 2; ++s) {
    int ck = ck2 * 2 + s;
    long tg0 = (long)b * 4096 + (long)ck * 256;
    if (s) __syncthreads();  // all reads of previous chunk's KL/VL/sdiag done
    // stage K chunk [256][64]
#pragma unroll
    for (int i = 0; i < 4; ++i) {
      int c = i * 8 + wq;
      int row = c * 8 + rl;
      int sc_ = ((l & 7) * 8) ^ ((row & 7) << 3);
      gl_lds16(Kg + (tg0 + row) * 1024 + (long)h * 64 + sc_, KL + c * 512);
    }
    // stage Vt tile [64 e][256 n]
#pragma unroll
    for (int i = 0; i < 4; ++i) {
      int c = i * 8 + wq;
      int e = 2 * c + (l >> 5);
      int sc_ = ((l & 31) * 8) ^ ((e & 7) << 3);
      gl_lds16(Vt + ((long)bh * 64 + e) * 4096 + (long)ck * 256 + sc_, VL + c * 512);
    }
    asm volatile("s_waitcnt vmcnt(0)" ::: "memory");
    __syncthreads();
    // per-token diag + mask (threads 0-255)
    if (tid < 256) {
      float sm = 0.f;
#pragma unroll
      for (int j = 0; j < 8; ++j) {
        bf16x8 v = *(const bf16x8*)(KL + tid * 64 + ((j * 8) ^ ((tid & 7) << 3)));
#pragma unroll
        for (int e = 0; e < 8; ++e) {
          float f = bf2f((u16)v[e]);
          sm += f * f;
        }
      }
      sdiag[tid] = sm * (1.f / 128.f);
      smask[tid] = mask[tg0 + tid];
    }
    __syncthreads();
    for (int sc = 0; sc < 4; ++sc) {
      // dd: D[tok][r], A = K rows (sc*64..), B = proj rows (rq..rq+31)
      f32x4 accT[4][2] = {};
#pragma unroll
      for (int kk = 0; kk < 2; ++kk) {
        bf16x8 aK[4];
#pragma unroll
        for (int m = 0; m < 4; ++m)
          aK[m] = *(const bf16x8*)(KL + (sc * 64 + m * 16 + lo) * 64 +
                                   ((kk * 32 + hi * 8) ^ ((lo & 7) << 3)));
#pragma unroll
        for (int m = 0; m < 4; ++m)
#pragma unroll
          for (int nf = 0; nf < 2; ++nf)
            accT[m][nf] = __builtin_amdgcn_mfma_f32_16x16x32_bf16(aK[m], bPreg[nf][kk], accT[m][nf], 0, 0, 0);
      }
      // online max over mask*dd (wave-wide), rescale accumulators
      float mloc = -3.4e38f;
#pragma unroll
      for (int m = 0; m < 4; ++m) {
        int tb = m * 16 + hi * 4;
#pragma unroll
        for (int r = 0; r < 4; ++r) {
          float mv = smask[sc * 64 + tb + r];
#pragma unroll
          for (int nf = 0; nf < 2; ++nf) mloc = fmaxf(mloc, mv * accT[m][nf][r]);
        }
      }
#pragma unroll
      for (int sft = 1; sft < 64; sft <<= 1) mloc = fmaxf(mloc, __shfl_xor(mloc, sft, 64));
      float nM = fmaxf(Mw, mloc);
      float rs = __builtin_exp2f((Mw - nM) * LOG2E);
#pragma unroll
      for (int m = 0; m < 2; ++m)
#pragma unroll
        for (int q = 0; q < 4; ++q) {
          acc_ks[m][q] *= rs;
#pragma unroll
          for (int nf = 0; nf < 4; ++nf) acc2[m][nf][q] *= rs;
        }
      Mw = nM;
      // kp-tilde epilogue -> kpL[r][tok] (own rows rq..rq+31)
#pragma unroll
      for (int m = 0; m < 4; ++m) {
        int tb = m * 16 + hi * 4;
        float mv[4], dg[4];
#pragma unroll
        for (int r = 0; r < 4; ++r) {
          int tk = sc * 64 + tb + r;
          mv[r] = smask[tk];
          dg[r] = sdiag[tk];
        }
#pragma unroll
        for (int nf = 0; nf < 2; ++nf) {
          int rr = rq + nf * 16 + lo;
          float v[4];
#pragma unroll
          for (int r = 0; r < 4; ++r) {
            float x = mv[r] * accT[m][nf][r] - mv[r] * mv[r] * dg[r] - Mw;
            v[r] = __builtin_exp2f(x * LOG2E);
          }
          uint2 pk;
          pk.x = cvtpk(v[0], v[1]);
          pk.y = cvtpk(v[2], v[3]);
          *(uint2*)(kpL + rr * 64 + (tb ^ ((lo & 7) << 3))) = pk;
        }
      }
      // ctx MFMA: D[r][e] += kp~[r][n] * Vt[e][n]; + ksum via ones;
      // wave 0 also accumulates unscaled vsum[e] = sum_n Vm[n][e]
#pragma unroll
      for (int kk = 0; kk < 2; ++kk) {
        bf16x8 aC[2], bV[4];
#pragma unroll
        for (int m = 0; m < 2; ++m)
          aC[m] = *(const bf16x8*)(kpL + (rq + m * 16 + lo) * 64 +
                                   ((kk * 32 + hi * 8) ^ ((lo & 7) << 3)));
#pragma unroll
        for (int nf = 0; nf < 4; ++nf)
          bV[nf] = *(const bf16x8*)(VL + (nf * 16 + lo) * 256 +
                                    ((sc * 64 + kk * 32 + hi * 8) ^ ((lo & 7) << 3)));
#pragma unroll
        for (int m = 0; m < 2; ++m) {
          acc_ks[m] = __builtin_amdgcn_mfma_f32_16x16x32_bf16(aC[m], ones, acc_ks[m], 0, 0, 0);
#pragma unroll
          for (int nf = 0; nf < 4; ++nf)
            acc2[m][nf] = __builtin_amdgcn_mfma_f32_16x16x32_bf16(aC[m], bV[nf], acc2[m][nf], 0, 0, 0);
        }
        if (wq == 0) {
#pragma unroll
          for (int nf = 0; nf < 4; ++nf)
            acc_vs[nf] = __builtin_amdgcn_mfma_f32_16x16x32_bf16(ones, bV[nf], acc_vs[nf], 0, 0, 0);
        }
      }
    }
  }
  // write partials: part (bf16) [(bh*8+ck2)*64 + e][256 r], ksum f32,
  // per-wave max, wave-0 vsum f32
  long pb = ((long)bh * 8 + ck2) * 64;
#pragma unroll
  for (int m = 0; m < 2; ++m) {
    int r0 = rq + m * 16 + hi * 4;
#pragma unroll
    for (int nf = 0; nf < 4; ++nf) {
      int e = nf * 16 + lo;
      uint2 pk;
      pk.x = cvtpk(acc2[m][nf][0], acc2[m][nf][1]);
      pk.y = cvtpk(acc2[m][nf][2], acc2[m][nf][3]);
      *(uint2*)&part[(pb + e) * 256 + r0] = pk;
    }
    if (lo == 0)
      *(f32x4*)&part_ks[((long)bh * 8 + ck2) * 256 + r0] = acc_ks[m];
  }
  if (l == 0) part_m[((long)bh * 8 + ck2) * 8 + wq] = Mw;
  if (wq == 0 && hi == 0) {
#pragma unroll
    for (int nf = 0; nf < 4; ++nf)
      part_vs[((long)bh * 8 + ck2) * 64 + nf * 16 + lo] = acc_vs[nf][0];
  }
}

// ---------------- reduce partials -> ctxb [bh][80][256] bf16 ----------------
__global__ __launch_bounds__(256) void ctx_reduce2(
    const u16* __restrict__ part, const float* __restrict__ part_ks,
    const float* __restrict__ part_m, const float* __restrict__ part_vs,
    u16* __restrict__ ctxb) {
  int bid = blockIdx.x;
  int bh = bid / 80, j = bid % 80;
  int r = threadIdx.x;
  const float* pm = part_m + (long)bh * 64;
  float M = -3.4e38f;
#pragma unroll
  for (int i = 0; i < 64; ++i) M = fmaxf(M, pm[i]);
  int wv = r >> 5;
  float out = 0.f;
  if (j < 64) {
    float s = 0.f, sv = 0.f;
#pragma unroll
    for (int c = 0; c < 8; ++c) {
      s += __builtin_exp2f((pm[c * 8 + wv] - M) * LOG2E) *
           bf2f(part[(((long)bh * 8 + c) * 64 + j) * 256 + r]);
      sv += part_vs[((long)bh * 8 + c) * 64 + j];
    }
    out = RATIO * (s + EPSK * sv);
  } else if (j == 64) {
    float s = 0.f;
#pragma unroll
    for (int c = 0; c < 8; ++c)
      s += __builtin_exp2f((pm[c * 8 + wv] - M) * LOG2E) *
           part_ks[((long)bh * 8 + c) * 256 + r];
    out = RATIO * (s + EPSK * 4096.f);
  }
  ctxb[((long)bh * 80 + j) * 256 + r] = f2bf(out);
}

// =====================================================================
// qattn: per (bh, 256-token block = 2 halves of 128): proj + ctxb staged
// ONCE; per half: recompute qp in LDS (dd transposed, cross-wave rowmax),
// then D2[j][tok] = ctxb[j][r]*qp[tok][r]; j=64 row is the denominator.
// Extra barrier before half-1's QL staging protects half-0's qpL reads
// (QL/qpL overlay).
// =====================================================================
__global__ __launch_bounds__(256) void qattn(
    const u16* __restrict__ Qg, const u16* __restrict__ Pbf,
    const u16* __restrict__ ctxbg, u16* __restrict__ attn) {
  __shared__ __align__(16) u16 L[69632];  // proj 16384 | ctxb 20480 | Q/qp 32768
  __shared__ float sdiagq[128];
  __shared__ float sredq[4 * 128];
  u16* projL = L;
  u16* CL = L + 16384;
  u16* QL = L + 36864;   // overlaid by qp after the rowmax barrier
  u16* qpL = L + 36864;  // [128 tok][256 r]
  int tid = threadIdx.x, l = tid & 63, wq = tid >> 6;
  int lo = l & 15, hi = l >> 4;
  int bh = blockIdx.x;
  int b = bh >> 4, h = bh & 15;
  int rq = wq * 64, tq = wq * 32;
  // stage proj (swizzled) -- once per block
#pragma unroll
  for (int i = 0; i < 8; ++i) {
    int c = wq * 8 + i;
    int row = c * 8 + (l >> 3);
    int sc_ = ((l & 7) * 8) ^ ((row & 7) << 3);
    gl_lds16(Pbf + (long)row * 64 + sc_, projL + c * 512);
  }
  // stage ctxb tile [80][256] (swizzled) -- once per block
#pragma unroll
  for (int i = 0; i < 10; ++i) {
    int c = wq * 10 + i;
    int j = 2 * c + (l >> 5);
    int sc_ = ((l & 31) * 8) ^ ((j & 7) << 3);
    gl_lds16(ctxbg + ((long)bh * 80 + j) * 256 + sc_, CL + c * 512);
  }

  for (int half = 0; half < 2; ++half) {
    long tokb = (long)b * 4096 + (long)blockIdx.y * 256 + (long)half * 128;
    if (half) __syncthreads();  // half-0's qpL reads done before re-staging QL
    // stage Q tile [128][64] (swizzled)
#pragma unroll
    for (int i = 0; i < 4; ++i) {
      int c = wq * 4 + i;
      int row = c * 8 + (l >> 3);
      int sc_ = ((l & 7) * 8) ^ ((row & 7) << 3);
      gl_lds16(Qg + (tokb + row) * 1024 + (long)h * 64 + sc_, QL + c * 512);
    }
    asm volatile("s_waitcnt vmcnt(0)" ::: "memory");
    __syncthreads();
    // diag per token (threads 0-127)
    if (tid < 128) {
      float s = 0.f;
#pragma unroll
      for (int j = 0; j < 8; ++j) {
        bf16x8 v = *(const bf16x8*)(QL + tid * 64 + ((j * 8) ^ ((tid & 7) << 3)));
#pragma unroll
        for (int e = 0; e < 8; ++e) {
          float f = bf2f((u16)v[e]);
          s += f * f;
        }
      }
      sdiagq[tid] = s * (1.f / 128.f);
    }
    // dd transposed: D[r][tok], A = proj rows r (wave quadrant), B = Q rows tok
    f32x4 acc[4][8];
#pragma unroll
    for (int m = 0; m < 4; ++m)
#pragma unroll
      for (int nf = 0; nf < 8; ++nf) acc[m][nf] = f32x4{0.f, 0.f, 0.f, 0.f};
#pragma unroll
    for (int kk = 0; kk < 2; ++kk) {
      bf16x8 aP[4], bQ[8];
#pragma unroll
      for (int m = 0; m < 4; ++m)
        aP[m] = *(const bf16x8*)(projL + (rq + m * 16 + lo) * 64 +
                                 ((kk * 32 + hi * 8) ^ ((lo & 7) << 3)));
#pragma unroll
      for (int nf = 0; nf < 8; ++nf)
        bQ[nf] = *(const bf16x8*)(QL + (nf * 16 + lo) * 64 +
                                  ((kk * 32 + hi * 8) ^ ((lo & 7) << 3)));
#pragma unroll
      for (int m = 0; m < 4; ++m)
#pragma unroll
        for (int nf = 0; nf < 8; ++nf)
          acc[m][nf] = __builtin_amdgcn_mfma_f32_16x16x32_bf16(aP[m], bQ[nf], acc[m][nf], 0, 0, 0);
    }
    // wave-local rowmax per token
#pragma unroll
    for (int nf = 0; nf < 8; ++nf) {
      float vm = acc[0][nf][0];
#pragma unroll
      for (int m = 0; m < 4; ++m)
#pragma unroll
        for (int r = 0; r < 4; ++r) vm = fmaxf(vm, acc[m][nf][r]);
      vm = fmaxf(vm, __shfl_xor(vm, 16, 64));
      vm = fmaxf(vm, __shfl_xor(vm, 32, 64));
      if (hi == 0) sredq[wq * 128 + nf * 16 + lo] = vm;
    }
    __syncthreads();  // also separates QL reads from qp writes
    // final rowmax + epilogue -> qpL[tok][r]
#pragma unroll
    for (int nf = 0; nf < 8; ++nf) {
      int tk = nf * 16 + lo;
      float rm = fmaxf(fmaxf(sredq[tk], sredq[128 + tk]),
                       fmaxf(sredq[256 + tk], sredq[384 + tk]));
      float dg = sdiagq[tk];
#pragma unroll
      for (int m = 0; m < 4; ++m) {
        int r0 = rq + m * 16 + hi * 4;
        float v[4];
#pragma unroll
        for (int r = 0; r < 4; ++r) {
          float x = acc[m][nf][r] - dg - rm;
          v[r] = RATIO * (__builtin_exp2f(x * LOG2E) + EPSK);
        }
        uint2 pk;
        pk.x = cvtpk(v[0], v[1]);
        pk.y = cvtpk(v[2], v[3]);
        *(uint2*)(qpL + tk * 256 + (r0 ^ ((lo & 7) << 3))) = pk;
      }
    }
    __syncthreads();
    // D2[j][tok] = sum_r ctxb[j][r] * qp[tok][r]; wave owns 32 tok
    f32x4 acc2[5][2];
#pragma unroll
    for (int m = 0; m < 5; ++m)
#pragma unroll
      for (int n = 0; n < 2; ++n) acc2[m][n] = f32x4{0.f, 0.f, 0.f, 0.f};
#pragma unroll
    for (int ks = 0; ks < 8; ++ks) {
      bf16x8 aC[5], bQp[2];
#pragma unroll
      for (int m = 0; m < 5; ++m)
        aC[m] = *(const bf16x8*)(CL + (m * 16 + lo) * 256 +
                                 ((ks * 32 + hi * 8) ^ ((lo & 7) << 3)));
#pragma unroll
      for (int n = 0; n < 2; ++n)
        bQp[n] = *(const bf16x8*)(qpL + (tq + n * 16 + lo) * 256 +
                                  ((ks * 32 + hi * 8) ^ ((lo & 7) << 3)));
#pragma unroll
      for (int m = 0; m < 5; ++m)
#pragma unroll
        for (int n = 0; n < 2; ++n)
          acc2[m][n] = __builtin_amdgcn_mfma_f32_16x16x32_bf16(aC[m], bQp[n], acc2[m][n], 0, 0, 0);
    }
    // epilogue: denom at j=64 (m=4, hi=0, reg=0) -> broadcast via shfl(lane = lo)
#pragma unroll
    for (int n = 0; n < 2; ++n) {
      float dv = __shfl(acc2[4][n][0], lo, 64);
      float di = 1.f / dv;
      long tok = tokb + tq + n * 16 + lo;
#pragma unroll
      for (int m = 0; m < 4; ++m) {
        int j0 = m * 16 + hi * 4;
        uint2 pk;
        pk.x = cvtpk(acc2[m][n][0] * di, acc2[m][n][1] * di);
        pk.y = cvtpk(acc2[m][n][2] * di, acc2[m][n][3] * di);
        *(uint2*)&attn[tok * 1024 + (long)h * 64 + j0] = pk;
      }
    }
  }
}

extern "C" void kernel_launch(void* const* d_in, const int* in_sizes, int n_in,
                              void* d_out, int out_size, void* d_ws, size_t ws_size,
                              hipStream_t stream) {
  const float* X = (const float*)d_in[0];
  const float* mask = (const float*)d_in[1];
  const float* Wq = (const float*)d_in[2];
  const float* bq = (const float*)d_in[3];
  const float* Wk = (const float*)d_in[4];
  const float* bk = (const float*)d_in[5];
  const float* Wv = (const float*)d_in[6];
  const float* bv = (const float*)d_in[7];
  const float* Wff = (const float*)d_in[8];
  const float* bff = (const float*)d_in[9];
  const float* proj = (const float*)d_in[10];
  float* out = (float*)d_out;

  char* p = (char*)d_ws;
  u16* Xbf = (u16*)p;   p += 16777216;   // [8192][1024] bf16; reused as attn
  u16* Wqkv = (u16*)p;  p += 6291456;    // [3072][1024]
  u16* Wffb = (u16*)p;  p += 2097152;    // [1024][1024]
  u16* Pbf = (u16*)p;   p += 32768;      // bf16(proj/8) [256][64]
  u16* Qbf = (u16*)p;   p += 16777216;
  u16* Kbf = (u16*)p;   p += 16777216;
  u16* Vt = (u16*)p;    p += 16777216;   // [bh*64+e][4096] (mask applied)
  u16* ctxb = (u16*)p;  p += 1310720;    // [bh][80][256]
  u16* part = (u16*)p;      p += 8388608;  // [bh*8][64][256] bf16
  float* part_ks = (float*)p; p += 262144; // [bh*8][256] f32
  float* part_m = (float*)p;  p += 8192;   // [bh*8][8] f32
  float* part_vs = (float*)p; p += 65536;  // [bh*8][64] f32
  u16* attn = Xbf;

  cvt_all<<<12304, 256, 0, stream>>>(X, Wq, Wk, Wv, Wff, proj, Xbf, Wqkv, Wffb, Pbf);
  gemmring<0, 24><<<768, 512, 0, stream>>>(Xbf, Wqkv, bq, bk, bv, mask, Qbf, Kbf, Vt, nullptr, nullptr);
  kctx<<<dim3(32, 8), 512, 0, stream>>>(Kbf, Pbf, Vt, mask, part, part_ks, part_m, part_vs);
  ctx_reduce2<<<2560, 256, 0, stream>>>(part, part_ks, part_m, part_vs, ctxb);
  qattn<<<dim3(32, 16), 256, 0, stream>>>(Qbf, Pbf, ctxb, attn);
  gemmring<1, 8><<<256, 512, 0, stream>>>(attn, Wffb, nullptr, nullptr, nullptr, nullptr,
                                          nullptr, nullptr, nullptr, out, bff);
}